// Round 3
// baseline (806.863 us; speedup 1.0000x reference)
//
#include <hip/hip_runtime.h>

#define N_NODES 100000
#define N_EDGES 1600000
#define D 64

// ---------------- workspace layout (bytes) ----------------
// off   : int[N+1]      @ 0
// deg   : int[N]        @ 400016
// cur   : int[N]        @ 800016
// bsum  : int[512]      @ 1200016
// sj    : int[E]        @ 1202064   (sorted neighbor j per CSR slot)
// wcomb : float[64*64]  @ 7602064   (mw2 @ aw1[64:128])
// bcomb : float[64]     @ 7618448   (mb2 @ aw1[64:128])
// Q     : float[N*64]   @ 7618704   (x @ mw1[64:128])
// total ~33.3 MB
#define WS_OFF   0
#define WS_DEG   400016
#define WS_CUR   800016
#define WS_BSUM  1200016
#define WS_SJ    1202064
#define WS_WCOMB 7602064
#define WS_BCOMB 7618448
#define WS_Q     7618704

__global__ void k_zero(int* deg) {
    int t = blockIdx.x * blockDim.x + threadIdx.x;
    if (t < N_NODES) deg[t] = 0;
}

__global__ void k_count(const int* __restrict__ ei, int* deg) {
    int e = blockIdx.x * blockDim.x + threadIdx.x;
    if (e < N_EDGES) atomicAdd(&deg[ei[e]], 1);
}

// block-level inclusive scan -> local exclusive + block sums
__global__ void k_scan1(const int* __restrict__ deg, int* off, int* bsum) {
    __shared__ int s[256];
    int t = blockIdx.x * 256 + threadIdx.x;
    int v = (t < N_NODES) ? deg[t] : 0;
    s[threadIdx.x] = v;
    __syncthreads();
    for (int o = 1; o < 256; o <<= 1) {
        int add = (threadIdx.x >= o) ? s[threadIdx.x - o] : 0;
        __syncthreads();
        s[threadIdx.x] += add;
        __syncthreads();
    }
    if (t < N_NODES) off[t] = s[threadIdx.x] - v;   // local exclusive
    if (threadIdx.x == 255) bsum[blockIdx.x] = s[255];
}

__global__ void k_scan2(int* bsum, int nb) {
    __shared__ int s[512];
    int v = (threadIdx.x < nb) ? bsum[threadIdx.x] : 0;
    s[threadIdx.x] = v;
    __syncthreads();
    for (int o = 1; o < 512; o <<= 1) {
        int add = (threadIdx.x >= o) ? s[threadIdx.x - o] : 0;
        __syncthreads();
        s[threadIdx.x] += add;
        __syncthreads();
    }
    if (threadIdx.x < nb) bsum[threadIdx.x] = s[threadIdx.x] - v;  // exclusive
}

__global__ void k_scan3(const int* __restrict__ deg, int* off,
                        const int* __restrict__ bsum, int* cur) {
    int t = blockIdx.x * 256 + threadIdx.x;
    if (t < N_NODES) {
        int o = off[t] + bsum[blockIdx.x];
        off[t] = o;
        cur[t] = o;
        if (t == N_NODES - 1) off[N_NODES] = o + deg[t];
    }
}

__global__ void k_fill(const int* __restrict__ ei, const int* __restrict__ ej,
                       int* cur, int* sj) {
    int e = blockIdx.x * blockDim.x + threadIdx.x;
    if (e < N_EDGES) {
        int i = ei[e];
        int p = atomicAdd(&cur[i], 1);
        sj[p] = ej[e];
    }
}

// wcomb[c][k] = sum_a mw2[c][a] * aw1[64+a][k];  bcomb[k] = sum_a mb2[a]*aw1[64+a][k]
__global__ void k_wcomb(const float* __restrict__ mw2, const float* __restrict__ mb2,
                        const float* __restrict__ aw1, float* wcomb, float* bcomb) {
    int o = blockIdx.x * blockDim.x + threadIdx.x;
    if (o < 64 * 64) {
        int c = o >> 6, k = o & 63;
        float s = 0.f;
        #pragma unroll 8
        for (int a = 0; a < 64; ++a) s += mw2[c * 64 + a] * aw1[(64 + a) * 64 + k];
        wcomb[o] = s;
    } else if (o < 64 * 64 + 64) {
        int k = o - 64 * 64;
        float s = 0.f;
        #pragma unroll 8
        for (int a = 0; a < 64; ++a) s += mb2[a] * aw1[(64 + a) * 64 + k];
        bcomb[k] = s;
    }
}

// Q = x @ mw1[64:128]   (one wave per node, lane = output feature)
__global__ void __launch_bounds__(256) k_q(const float* __restrict__ x,
                                           const float* __restrict__ mw1,
                                           float* __restrict__ Q) {
    __shared__ float w[64 * 64];
    for (int t = threadIdx.x; t < 64 * 64; t += 256) w[t] = mw1[64 * 64 + t];
    __syncthreads();
    int wave = threadIdx.x >> 6, lane = threadIdx.x & 63;
    int node = blockIdx.x * 4 + wave;
    if (node >= N_NODES) return;
    float xv = x[node * 64 + lane];
    float acc = 0.f;
    #pragma unroll
    for (int c = 0; c < 64; ++c) acc += __shfl(xv, c, 64) * w[c * 64 + lane];
    Q[node * 64 + lane] = acc;
}

// Edge aggregation: one wave per node. P = x_i@W1a + mb1 (loop-invariant),
// per edge: relu(P + Q[j] + dpos@W1p), mean over edges -> stored in d_out (temp).
__global__ void __launch_bounds__(256) k_c1(const float* __restrict__ x,
                                            const float* __restrict__ pos,
                                            const float* __restrict__ mw1,
                                            const float* __restrict__ mb1,
                                            const float* __restrict__ Q,
                                            const int* __restrict__ off,
                                            const int* __restrict__ sj,
                                            float* __restrict__ outh) {
    __shared__ float w1a[64 * 64];
    __shared__ float w1p[3 * 64];
    __shared__ float bias[64];
    for (int t = threadIdx.x; t < 64 * 64; t += 256) w1a[t] = mw1[t];
    for (int t = threadIdx.x; t < 3 * 64; t += 256) w1p[t] = mw1[128 * 64 + t];
    if (threadIdx.x < 64) bias[threadIdx.x] = mb1[threadIdx.x];
    __syncthreads();
    int wave = threadIdx.x >> 6, lane = threadIdx.x & 63;
    int node = blockIdx.x * 4 + wave;
    if (node >= N_NODES) return;

    float xv = x[node * 64 + lane];
    float P = bias[lane];
    #pragma unroll
    for (int c = 0; c < 64; ++c) P += __shfl(xv, c, 64) * w1a[c * 64 + lane];

    float pix = pos[node * 3 + 0], piy = pos[node * 3 + 1], piz = pos[node * 3 + 2];
    float wpx = w1p[lane], wpy = w1p[64 + lane], wpz = w1p[128 + lane];
    int o0 = off[node], o1 = off[node + 1];
    float acc = 0.f;
    for (int base = o0; base < o1; base += 64) {
        int m = min(64, o1 - base);
        int jv = (lane < m) ? sj[base + lane] : 0;
        #pragma unroll 4
        for (int c = 0; c < m; ++c) {
            int jc = __builtin_amdgcn_readlane(jv, c);   // SGPR -> scalar addr math
            float djx = pos[jc * 3 + 0] - pix;
            float djy = pos[jc * 3 + 1] - piy;
            float djz = pos[jc * 3 + 2] - piz;
            float qv = Q[jc * 64 + lane];                // coalesced 256B gather
            float pre = P + qv + djx * wpx + djy * wpy + djz * wpz;
            acc += fmaxf(pre, 0.f);
        }
    }
    int dg = o1 - o0;
    outh[node * 64 + lane] = (dg > 0) ? acc / (float)dg : 0.f;
}

// Node update: out = relu(x@aw1_top + hmean@Wcomb + bcomb + ab1) @ aw2 + ab2
__global__ void __launch_bounds__(256) k_c2(const float* __restrict__ x,
                                            const float* __restrict__ aw1,
                                            const float* __restrict__ ab1,
                                            const float* __restrict__ wcomb,
                                            const float* __restrict__ bcomb,
                                            const float* __restrict__ aw2,
                                            const float* __restrict__ ab2,
                                            const int* __restrict__ deg,
                                            float* __restrict__ out) {
    __shared__ float at[64 * 64];
    __shared__ float wc[64 * 64];
    __shared__ float w2[64 * 64];
    for (int t = threadIdx.x; t < 64 * 64; t += 256) {
        at[t] = aw1[t];
        wc[t] = wcomb[t];
        w2[t] = aw2[t];
    }
    __syncthreads();
    int wave = threadIdx.x >> 6, lane = threadIdx.x & 63;
    int node = blockIdx.x * 4 + wave;
    if (node >= N_NODES) return;

    float xv = x[node * 64 + lane];
    float hm = out[node * 64 + lane];     // hmean written by k_c1 (in-place temp)
    float t1 = ab1[lane];
    #pragma unroll
    for (int c = 0; c < 64; ++c) t1 += __shfl(xv, c, 64) * at[c * 64 + lane];
    if (deg[node] > 0) {
        t1 += bcomb[lane];
        #pragma unroll
        for (int c = 0; c < 64; ++c) t1 += __shfl(hm, c, 64) * wc[c * 64 + lane];
    }
    float h2 = fmaxf(t1, 0.f);
    float o = ab2[lane];
    #pragma unroll
    for (int c = 0; c < 64; ++c) o += __shfl(h2, c, 64) * w2[c * 64 + lane];
    out[node * 64 + lane] = o;
}

extern "C" void kernel_launch(void* const* d_in, const int* in_sizes, int n_in,
                              void* d_out, int out_size, void* d_ws, size_t ws_size,
                              hipStream_t stream) {
    const float* x   = (const float*)d_in[0];
    const int*   ei  = (const int*)d_in[1];              // edge_index[0] = target i
    const int*   ej  = ((const int*)d_in[1]) + N_EDGES;  // edge_index[1] = source j
    const float* pos = (const float*)d_in[2];
    const float* mw1 = (const float*)d_in[3];
    const float* mb1 = (const float*)d_in[4];
    const float* mw2 = (const float*)d_in[5];
    const float* mb2 = (const float*)d_in[6];
    const float* aw1 = (const float*)d_in[7];
    const float* ab1 = (const float*)d_in[8];
    const float* aw2 = (const float*)d_in[9];
    const float* ab2 = (const float*)d_in[10];

    char* ws = (char*)d_ws;
    int*   off   = (int*)(ws + WS_OFF);
    int*   deg   = (int*)(ws + WS_DEG);
    int*   cur   = (int*)(ws + WS_CUR);
    int*   bsum  = (int*)(ws + WS_BSUM);
    int*   sj    = (int*)(ws + WS_SJ);
    float* wcomb = (float*)(ws + WS_WCOMB);
    float* bcomb = (float*)(ws + WS_BCOMB);
    float* Q     = (float*)(ws + WS_Q);
    float* out   = (float*)d_out;

    const int NB1 = (N_NODES + 255) / 256;  // 391
    hipLaunchKernelGGL(k_zero,  dim3(NB1), dim3(256), 0, stream, deg);
    hipLaunchKernelGGL(k_count, dim3((N_EDGES + 255) / 256), dim3(256), 0, stream, ei, deg);
    hipLaunchKernelGGL(k_scan1, dim3(NB1), dim3(256), 0, stream, deg, off, bsum);
    hipLaunchKernelGGL(k_scan2, dim3(1), dim3(512), 0, stream, bsum, NB1);
    hipLaunchKernelGGL(k_scan3, dim3(NB1), dim3(256), 0, stream, deg, off, bsum, cur);
    hipLaunchKernelGGL(k_fill,  dim3((N_EDGES + 255) / 256), dim3(256), 0, stream, ei, ej, cur, sj);
    hipLaunchKernelGGL(k_wcomb, dim3(17), dim3(256), 0, stream, mw2, mb2, aw1, wcomb, bcomb);
    hipLaunchKernelGGL(k_q,     dim3((N_NODES + 3) / 4), dim3(256), 0, stream, x, mw1, Q);
    hipLaunchKernelGGL(k_c1,    dim3((N_NODES + 3) / 4), dim3(256), 0, stream,
                       x, pos, mw1, mb1, Q, off, sj, out);
    hipLaunchKernelGGL(k_c2,    dim3((N_NODES + 3) / 4), dim3(256), 0, stream,
                       x, aw1, ab1, wcomb, bcomb, aw2, ab2, deg, out);
}

// Round 4
// 395.731 us; speedup vs baseline: 2.0389x; 2.0389x over previous
//
#include <hip/hip_runtime.h>

#define N_NODES 100000
#define N_EDGES 1600000

// ---------------- workspace layout (bytes) ----------------
// off   : int[N+1]      @ 0
// deg   : int[N]        @ 400016
// cur   : int[N]        @ 800016
// bsum  : int[512]      @ 1200016
// sj    : int[E]        @ 1202064
// wcomb : float[64*64]  @ 7602064
// bcomb : float[64]     @ 7618448
// Q     : float[N*64]   @ 7618704
// total ~33.2 MB   (P lives in d_out as a temp)
#define WS_OFF   0
#define WS_DEG   400016
#define WS_CUR   800016
#define WS_BSUM  1200016
#define WS_SJ    1202064
#define WS_WCOMB 7602064
#define WS_BCOMB 7618448
#define WS_Q     7618704

#define XP 68   // padded LDS row pitch (floats): 68*4B=272B, 16B-aligned, bank-spread

__global__ void k_zero(int* deg) {
    int t = blockIdx.x * blockDim.x + threadIdx.x;
    if (t < N_NODES) deg[t] = 0;
}

__global__ void k_count(const int* __restrict__ ei, int* deg) {
    int e = blockIdx.x * blockDim.x + threadIdx.x;
    if (e < N_EDGES) atomicAdd(&deg[ei[e]], 1);
}

__global__ void k_scan1(const int* __restrict__ deg, int* off, int* bsum) {
    __shared__ int s[256];
    int t = blockIdx.x * 256 + threadIdx.x;
    int v = (t < N_NODES) ? deg[t] : 0;
    s[threadIdx.x] = v;
    __syncthreads();
    for (int o = 1; o < 256; o <<= 1) {
        int add = (threadIdx.x >= o) ? s[threadIdx.x - o] : 0;
        __syncthreads();
        s[threadIdx.x] += add;
        __syncthreads();
    }
    if (t < N_NODES) off[t] = s[threadIdx.x] - v;
    if (threadIdx.x == 255) bsum[blockIdx.x] = s[255];
}

__global__ void k_scan2(int* bsum, int nb) {
    __shared__ int s[512];
    int v = (threadIdx.x < nb) ? bsum[threadIdx.x] : 0;
    s[threadIdx.x] = v;
    __syncthreads();
    for (int o = 1; o < 512; o <<= 1) {
        int add = (threadIdx.x >= o) ? s[threadIdx.x - o] : 0;
        __syncthreads();
        s[threadIdx.x] += add;
        __syncthreads();
    }
    if (threadIdx.x < nb) bsum[threadIdx.x] = s[threadIdx.x] - v;
}

__global__ void k_scan3(const int* __restrict__ deg, int* off,
                        const int* __restrict__ bsum, int* cur) {
    int t = blockIdx.x * 256 + threadIdx.x;
    if (t < N_NODES) {
        int o = off[t] + bsum[blockIdx.x];
        off[t] = o;
        cur[t] = o;
        if (t == N_NODES - 1) off[N_NODES] = o + deg[t];
    }
}

__global__ void k_fill(const int* __restrict__ ei, const int* __restrict__ ej,
                       int* cur, int* sj) {
    int e = blockIdx.x * blockDim.x + threadIdx.x;
    if (e < N_EDGES) {
        int i = ei[e];
        int p = atomicAdd(&cur[i], 1);
        sj[p] = ej[e];
    }
}

__global__ void k_wcomb(const float* __restrict__ mw2, const float* __restrict__ mb2,
                        const float* __restrict__ aw1, float* wcomb, float* bcomb) {
    int o = blockIdx.x * blockDim.x + threadIdx.x;
    if (o < 64 * 64) {
        int c = o >> 6, k = o & 63;
        float s = 0.f;
        #pragma unroll 8
        for (int a = 0; a < 64; ++a) s += mw2[c * 64 + a] * aw1[(64 + a) * 64 + k];
        wcomb[o] = s;
    } else if (o < 64 * 64 + 64) {
        int k = o - 64 * 64;
        float s = 0.f;
        #pragma unroll 8
        for (int a = 0; a < 64; ++a) s += mb2[a] * aw1[(64 + a) * 64 + k];
        bcomb[k] = s;
    }
}

// ---- shared GEMM building blocks: BM=128, BN=64, thread tile 8m x 4f ----
// thread t: tx = t&15 -> f0 = 4*tx ; ty = t>>4 -> m = 16*i + ty (i=0..7)

__device__ __forceinline__ void stage_x(float* xs, const float* src, int m0) {
    int t = threadIdx.x;
    #pragma unroll
    for (int it = 0; it < 8; ++it) {
        int idx = it * 256 + t;        // 0..2047
        int m = idx >> 4;              // 0..127
        int q = idx & 15;              // float4 index in row
        float4 v = make_float4(0.f, 0.f, 0.f, 0.f);
        if (m0 + m < N_NODES) v = *(const float4*)(src + (size_t)(m0 + m) * 64 + q * 4);
        *(float4*)(xs + m * XP + q * 4) = v;
    }
}

__device__ __forceinline__ void stage_w(float* ws, const float* src) {
    int t = threadIdx.x;
    #pragma unroll
    for (int it = 0; it < 4; ++it) {
        int idx = it * 256 + t;
        *(float4*)(ws + idx * 4) = *(const float4*)(src + idx * 4);
    }
}

__device__ __forceinline__ void gemm_acc(const float* xs, const float* ws,
                                         int ty, int f0, float4 acc[8]) {
    #pragma unroll 4
    for (int k4 = 0; k4 < 64; k4 += 4) {
        float4 b0 = *(const float4*)(ws + (k4 + 0) * 64 + f0);
        float4 b1 = *(const float4*)(ws + (k4 + 1) * 64 + f0);
        float4 b2 = *(const float4*)(ws + (k4 + 2) * 64 + f0);
        float4 b3 = *(const float4*)(ws + (k4 + 3) * 64 + f0);
        #pragma unroll
        for (int i = 0; i < 8; ++i) {
            float4 a = *(const float4*)(xs + (i * 16 + ty) * XP + k4);
            float4 c = acc[i];
            c.x = fmaf(a.x, b0.x, c.x); c.y = fmaf(a.x, b0.y, c.y);
            c.z = fmaf(a.x, b0.z, c.z); c.w = fmaf(a.x, b0.w, c.w);
            c.x = fmaf(a.y, b1.x, c.x); c.y = fmaf(a.y, b1.y, c.y);
            c.z = fmaf(a.y, b1.z, c.z); c.w = fmaf(a.y, b1.w, c.w);
            c.x = fmaf(a.z, b2.x, c.x); c.y = fmaf(a.z, b2.y, c.y);
            c.z = fmaf(a.z, b2.z, c.z); c.w = fmaf(a.z, b2.w, c.w);
            c.x = fmaf(a.w, b3.x, c.x); c.y = fmaf(a.w, b3.y, c.y);
            c.z = fmaf(a.w, b3.z, c.z); c.w = fmaf(a.w, b3.w, c.w);
            acc[i] = c;
        }
    }
}

// P = x@mw1[0:64] + mb1 (y=0, -> d_out temp) ; Q = x@mw1[64:128] (y=1, -> ws Q)
__global__ void __launch_bounds__(256) k_pre(const float* __restrict__ x,
                                             const float* __restrict__ mw1,
                                             const float* __restrict__ mb1,
                                             float* __restrict__ P,
                                             float* __restrict__ Q) {
    __shared__ float xs[128 * XP];
    __shared__ float ws[64 * 64];
    int half = blockIdx.y;
    int m0 = blockIdx.x * 128;
    stage_x(xs, x, m0);
    stage_w(ws, mw1 + half * 4096);
    __syncthreads();
    int t = threadIdx.x, tx = t & 15, ty = t >> 4, f0 = tx * 4;
    float4 acc[8];
    #pragma unroll
    for (int i = 0; i < 8; ++i) acc[i] = make_float4(0.f, 0.f, 0.f, 0.f);
    gemm_acc(xs, ws, ty, f0, acc);
    float* dst = half ? Q : P;
    float4 bias = make_float4(0.f, 0.f, 0.f, 0.f);
    if (!half) bias = *(const float4*)(mb1 + f0);
    #pragma unroll
    for (int i = 0; i < 8; ++i) {
        int m = m0 + i * 16 + ty;
        if (m < N_NODES) {
            float4 c = acc[i];
            c.x += bias.x; c.y += bias.y; c.z += bias.z; c.w += bias.w;
            *(float4*)(dst + (size_t)m * 64 + f0) = c;
        }
    }
}

// Edge aggregation: one wave per node; hmean = mean(relu(P_i + Q_j + dpos@W1p)).
// P lives in d_out; hmean overwrites the same row (owner-computes, safe).
__global__ void __launch_bounds__(256) k_c1(const float* __restrict__ pos,
                                            const float* __restrict__ mw1,
                                            const float* __restrict__ Q,
                                            const int* __restrict__ off,
                                            const int* __restrict__ sj,
                                            float* Phm) {
    int wave = threadIdx.x >> 6, lane = threadIdx.x & 63;
    int node = blockIdx.x * 4 + wave;
    if (node >= N_NODES) return;
    float Pv  = Phm[(size_t)node * 64 + lane];
    float wpx = mw1[128 * 64 + lane];
    float wpy = mw1[129 * 64 + lane];
    float wpz = mw1[130 * 64 + lane];
    float pix = pos[node * 3 + 0], piy = pos[node * 3 + 1], piz = pos[node * 3 + 2];
    int o0 = off[node], o1 = off[node + 1];
    float acc = 0.f;
    for (int base = o0; base < o1; base += 64) {
        int m = min(64, o1 - base);
        int jv = (lane < m) ? sj[base + lane] : 0;
        #pragma unroll 4
        for (int c = 0; c < m; ++c) {
            int jc = __builtin_amdgcn_readlane(jv, c);
            float djx = pos[jc * 3 + 0] - pix;
            float djy = pos[jc * 3 + 1] - piy;
            float djz = pos[jc * 3 + 2] - piz;
            float pre = Pv + Q[(size_t)jc * 64 + lane]
                      + djx * wpx + djy * wpy + djz * wpz;
            acc += fmaxf(pre, 0.f);
        }
    }
    int dg = o1 - o0;
    Phm[(size_t)node * 64 + lane] = (dg > 0) ? acc / (float)dg : 0.f;
}

// out = relu(x@aw1_top + hm@wcomb + ab1 + [deg>0]*bcomb) @ aw2 + ab2
// hm is read from d_out (written by k_c1); out overwrites the same rows.
__global__ void __launch_bounds__(256) k_c2(const float* __restrict__ x,
                                            const float* hm_in,
                                            const float* __restrict__ aw1,
                                            const float* __restrict__ ab1,
                                            const float* __restrict__ wcomb,
                                            const float* __restrict__ bcomb,
                                            const float* __restrict__ aw2,
                                            const float* __restrict__ ab2,
                                            const int* __restrict__ deg,
                                            float* out) {
    __shared__ float xs[128 * XP];
    __shared__ float ws[64 * 64];
    int m0 = blockIdx.x * 128;
    int t = threadIdx.x, tx = t & 15, ty = t >> 4, f0 = tx * 4;
    float4 acc[8];
    #pragma unroll
    for (int i = 0; i < 8; ++i) acc[i] = make_float4(0.f, 0.f, 0.f, 0.f);

    // phase 1: x @ aw1_top
    stage_x(xs, x, m0);
    stage_w(ws, aw1);
    __syncthreads();
    gemm_acc(xs, ws, ty, f0, acc);
    __syncthreads();

    // phase 2: + hm @ wcomb
    stage_x(xs, hm_in, m0);
    stage_w(ws, wcomb);
    __syncthreads();
    gemm_acc(xs, ws, ty, f0, acc);
    __syncthreads();

    // bias + relu -> h2 into xs; stage aw2 into ws
    float4 b1v = *(const float4*)(ab1 + f0);
    float4 bcv = *(const float4*)(bcomb + f0);
    #pragma unroll
    for (int i = 0; i < 8; ++i) {
        int m = m0 + i * 16 + ty;
        int dg = (m < N_NODES) ? deg[m] : 0;
        float4 c = acc[i];
        float bx = b1v.x, by = b1v.y, bz = b1v.z, bw = b1v.w;
        if (dg > 0) { bx += bcv.x; by += bcv.y; bz += bcv.z; bw += bcv.w; }
        c.x = fmaxf(c.x + bx, 0.f);
        c.y = fmaxf(c.y + by, 0.f);
        c.z = fmaxf(c.z + bz, 0.f);
        c.w = fmaxf(c.w + bw, 0.f);
        *(float4*)(xs + (i * 16 + ty) * XP + f0) = c;
    }
    stage_w(ws, aw2);
    __syncthreads();

    // phase 3: out = h2 @ aw2 + ab2
    float4 a2[8];
    #pragma unroll
    for (int i = 0; i < 8; ++i) a2[i] = make_float4(0.f, 0.f, 0.f, 0.f);
    gemm_acc(xs, ws, ty, f0, a2);
    float4 b2v = *(const float4*)(ab2 + f0);
    #pragma unroll
    for (int i = 0; i < 8; ++i) {
        int m = m0 + i * 16 + ty;
        if (m < N_NODES) {
            float4 c = a2[i];
            c.x += b2v.x; c.y += b2v.y; c.z += b2v.z; c.w += b2v.w;
            *(float4*)(out + (size_t)m * 64 + f0) = c;
        }
    }
}

extern "C" void kernel_launch(void* const* d_in, const int* in_sizes, int n_in,
                              void* d_out, int out_size, void* d_ws, size_t ws_size,
                              hipStream_t stream) {
    const float* x   = (const float*)d_in[0];
    const int*   ei  = (const int*)d_in[1];
    const int*   ej  = ((const int*)d_in[1]) + N_EDGES;
    const float* pos = (const float*)d_in[2];
    const float* mw1 = (const float*)d_in[3];
    const float* mb1 = (const float*)d_in[4];
    const float* mw2 = (const float*)d_in[5];
    const float* mb2 = (const float*)d_in[6];
    const float* aw1 = (const float*)d_in[7];
    const float* ab1 = (const float*)d_in[8];
    const float* aw2 = (const float*)d_in[9];
    const float* ab2 = (const float*)d_in[10];

    char* ws = (char*)d_ws;
    int*   off   = (int*)(ws + WS_OFF);
    int*   deg   = (int*)(ws + WS_DEG);
    int*   cur   = (int*)(ws + WS_CUR);
    int*   bsum  = (int*)(ws + WS_BSUM);
    int*   sj    = (int*)(ws + WS_SJ);
    float* wcomb = (float*)(ws + WS_WCOMB);
    float* bcomb = (float*)(ws + WS_BCOMB);
    float* Q     = (float*)(ws + WS_Q);
    float* out   = (float*)d_out;

    const int NB1 = (N_NODES + 255) / 256;   // 391
    const int NBT = (N_NODES + 127) / 128;   // 782
    hipLaunchKernelGGL(k_zero,  dim3(NB1), dim3(256), 0, stream, deg);
    hipLaunchKernelGGL(k_count, dim3((N_EDGES + 255) / 256), dim3(256), 0, stream, ei, deg);
    hipLaunchKernelGGL(k_scan1, dim3(NB1), dim3(256), 0, stream, deg, off, bsum);
    hipLaunchKernelGGL(k_scan2, dim3(1), dim3(512), 0, stream, bsum, NB1);
    hipLaunchKernelGGL(k_scan3, dim3(NB1), dim3(256), 0, stream, deg, off, bsum, cur);
    hipLaunchKernelGGL(k_fill,  dim3((N_EDGES + 255) / 256), dim3(256), 0, stream, ei, ej, cur, sj);
    hipLaunchKernelGGL(k_wcomb, dim3(17), dim3(256), 0, stream, mw2, mb2, aw1, wcomb, bcomb);
    hipLaunchKernelGGL(k_pre,   dim3(NBT, 2), dim3(256), 0, stream, x, mw1, mb1, out, Q);
    hipLaunchKernelGGL(k_c1,    dim3((N_NODES + 3) / 4), dim3(256), 0, stream,
                       pos, mw1, Q, off, sj, out);
    hipLaunchKernelGGL(k_c2,    dim3(NBT), dim3(256), 0, stream,
                       x, out, aw1, ab1, wcomb, bcomb, aw2, ab2, deg, out);
}

// Round 5
// 356.109 us; speedup vs baseline: 2.2658x; 1.1113x over previous
//
#include <hip/hip_runtime.h>

#define N_NODES 100000
#define N_EDGES 1600000
#define NPART 8
#define PSZ 12500          // N_NODES / NPART
#define ECHUNK 16384       // edges per block in partitioned scan
#define NCHUNK ((N_EDGES + ECHUNK - 1) / ECHUNK)   // 98

// ---------------- workspace layout (bytes) ----------------
#define WS_OFF   0                 // int[N+1]
#define WS_DEG   400016            // int[N]
#define WS_CUR   800016            // int[N]
#define WS_BSUM  1200016           // int[512]
#define WS_SJ    1202064           // int[E]        (6.4 MB)
#define WS_WCOMB 7602064           // float[64*64]
#define WS_BCOMB 7618448           // float[64]
#define WS_Q     7618704           // float[N*64]   (25.6 MB)
#define WS_POS4  33218704          // float4[N]     (1.6 MB)  total ~34.9 MB

#define XP 68   // padded LDS row pitch (floats)

// deg zero + pos4 pack in one pass
__global__ void k_init(const float* __restrict__ pos, int* deg, float4* pos4) {
    int t = blockIdx.x * blockDim.x + threadIdx.x;
    if (t < N_NODES) {
        deg[t] = 0;
        pos4[t] = make_float4(pos[3 * t], pos[3 * t + 1], pos[3 * t + 2], 0.f);
    }
}

// partitioned degree count: p = blockIdx%8 -> node range [p*PSZ, (p+1)*PSZ)
__global__ void __launch_bounds__(256) k_count(const int* __restrict__ ei, int* deg) {
    int p = blockIdx.x & (NPART - 1);
    int chunk = blockIdx.x / NPART;
    int lo = p * PSZ, hi = lo + PSZ;
    #pragma unroll 2
    for (int it = 0; it < ECHUNK / 1024; ++it) {
        int e0 = chunk * ECHUNK + it * 1024 + threadIdx.x * 4;
        if (e0 >= N_EDGES) break;
        int4 iv = *(const int4*)(ei + e0);
        if (iv.x >= lo && iv.x < hi) atomicAdd(&deg[iv.x], 1);
        if (iv.y >= lo && iv.y < hi) atomicAdd(&deg[iv.y], 1);
        if (iv.z >= lo && iv.z < hi) atomicAdd(&deg[iv.z], 1);
        if (iv.w >= lo && iv.w < hi) atomicAdd(&deg[iv.w], 1);
    }
}

__global__ void k_scan1(const int* __restrict__ deg, int* off, int* bsum) {
    __shared__ int s[256];
    int t = blockIdx.x * 256 + threadIdx.x;
    int v = (t < N_NODES) ? deg[t] : 0;
    s[threadIdx.x] = v;
    __syncthreads();
    for (int o = 1; o < 256; o <<= 1) {
        int add = (threadIdx.x >= o) ? s[threadIdx.x - o] : 0;
        __syncthreads();
        s[threadIdx.x] += add;
        __syncthreads();
    }
    if (t < N_NODES) off[t] = s[threadIdx.x] - v;
    if (threadIdx.x == 255) bsum[blockIdx.x] = s[255];
}

__global__ void k_scan2(int* bsum, int nb) {
    __shared__ int s[512];
    int v = (threadIdx.x < nb) ? bsum[threadIdx.x] : 0;
    s[threadIdx.x] = v;
    __syncthreads();
    for (int o = 1; o < 512; o <<= 1) {
        int add = (threadIdx.x >= o) ? s[threadIdx.x - o] : 0;
        __syncthreads();
        s[threadIdx.x] += add;
        __syncthreads();
    }
    if (threadIdx.x < nb) bsum[threadIdx.x] = s[threadIdx.x] - v;
}

__global__ void k_scan3(const int* __restrict__ deg, int* off,
                        const int* __restrict__ bsum, int* cur) {
    int t = blockIdx.x * 256 + threadIdx.x;
    if (t < N_NODES) {
        int o = off[t] + bsum[blockIdx.x];
        off[t] = o;
        cur[t] = o;
        if (t == N_NODES - 1) off[N_NODES] = o + deg[t];
    }
}

// partitioned CSR fill: stores land in the local XCD's L2 slice of sj
__global__ void __launch_bounds__(256) k_fill(const int* __restrict__ ei,
                                              const int* __restrict__ ej,
                                              int* cur, int* sj) {
    int p = blockIdx.x & (NPART - 1);
    int chunk = blockIdx.x / NPART;
    int lo = p * PSZ, hi = lo + PSZ;
    #pragma unroll 2
    for (int it = 0; it < ECHUNK / 1024; ++it) {
        int e0 = chunk * ECHUNK + it * 1024 + threadIdx.x * 4;
        if (e0 >= N_EDGES) break;
        int4 iv = *(const int4*)(ei + e0);
        int4 jv = *(const int4*)(ej + e0);
        if (iv.x >= lo && iv.x < hi) sj[atomicAdd(&cur[iv.x], 1)] = jv.x;
        if (iv.y >= lo && iv.y < hi) sj[atomicAdd(&cur[iv.y], 1)] = jv.y;
        if (iv.z >= lo && iv.z < hi) sj[atomicAdd(&cur[iv.z], 1)] = jv.z;
        if (iv.w >= lo && iv.w < hi) sj[atomicAdd(&cur[iv.w], 1)] = jv.w;
    }
}

__global__ void k_wcomb(const float* __restrict__ mw2, const float* __restrict__ mb2,
                        const float* __restrict__ aw1, float* wcomb, float* bcomb) {
    int o = blockIdx.x * blockDim.x + threadIdx.x;
    if (o < 64 * 64) {
        int c = o >> 6, k = o & 63;
        float s = 0.f;
        #pragma unroll 8
        for (int a = 0; a < 64; ++a) s += mw2[c * 64 + a] * aw1[(64 + a) * 64 + k];
        wcomb[o] = s;
    } else if (o < 64 * 64 + 64) {
        int k = o - 64 * 64;
        float s = 0.f;
        #pragma unroll 8
        for (int a = 0; a < 64; ++a) s += mb2[a] * aw1[(64 + a) * 64 + k];
        bcomb[k] = s;
    }
}

// ---- tiled GEMM blocks: BM=128, BN=64, thread tile 8m x 4f ----
__device__ __forceinline__ void stage_x(float* xs, const float* src, int m0) {
    int t = threadIdx.x;
    #pragma unroll
    for (int it = 0; it < 8; ++it) {
        int idx = it * 256 + t;
        int m = idx >> 4;
        int q = idx & 15;
        float4 v = make_float4(0.f, 0.f, 0.f, 0.f);
        if (m0 + m < N_NODES) v = *(const float4*)(src + (size_t)(m0 + m) * 64 + q * 4);
        *(float4*)(xs + m * XP + q * 4) = v;
    }
}

__device__ __forceinline__ void stage_w(float* ws, const float* src) {
    int t = threadIdx.x;
    #pragma unroll
    for (int it = 0; it < 4; ++it) {
        int idx = it * 256 + t;
        *(float4*)(ws + idx * 4) = *(const float4*)(src + idx * 4);
    }
}

__device__ __forceinline__ void gemm_acc(const float* xs, const float* ws,
                                         int ty, int f0, float4 acc[8]) {
    #pragma unroll 4
    for (int k4 = 0; k4 < 64; k4 += 4) {
        float4 b0 = *(const float4*)(ws + (k4 + 0) * 64 + f0);
        float4 b1 = *(const float4*)(ws + (k4 + 1) * 64 + f0);
        float4 b2 = *(const float4*)(ws + (k4 + 2) * 64 + f0);
        float4 b3 = *(const float4*)(ws + (k4 + 3) * 64 + f0);
        #pragma unroll
        for (int i = 0; i < 8; ++i) {
            float4 a = *(const float4*)(xs + (i * 16 + ty) * XP + k4);
            float4 c = acc[i];
            c.x = fmaf(a.x, b0.x, c.x); c.y = fmaf(a.x, b0.y, c.y);
            c.z = fmaf(a.x, b0.z, c.z); c.w = fmaf(a.x, b0.w, c.w);
            c.x = fmaf(a.y, b1.x, c.x); c.y = fmaf(a.y, b1.y, c.y);
            c.z = fmaf(a.y, b1.z, c.z); c.w = fmaf(a.y, b1.w, c.w);
            c.x = fmaf(a.z, b2.x, c.x); c.y = fmaf(a.z, b2.y, c.y);
            c.z = fmaf(a.z, b2.z, c.z); c.w = fmaf(a.z, b2.w, c.w);
            c.x = fmaf(a.w, b3.x, c.x); c.y = fmaf(a.w, b3.y, c.y);
            c.z = fmaf(a.w, b3.z, c.z); c.w = fmaf(a.w, b3.w, c.w);
            acc[i] = c;
        }
    }
}

// P = x@mw1[0:64] + mb1 (y=0 -> d_out temp); Q = x@mw1[64:128] (y=1 -> ws Q)
__global__ void __launch_bounds__(256) k_pre(const float* __restrict__ x,
                                             const float* __restrict__ mw1,
                                             const float* __restrict__ mb1,
                                             float* __restrict__ P,
                                             float* __restrict__ Q) {
    __shared__ float xs[128 * XP];
    __shared__ float ws[64 * 64];
    int half = blockIdx.y;
    int m0 = blockIdx.x * 128;
    stage_x(xs, x, m0);
    stage_w(ws, mw1 + half * 4096);
    __syncthreads();
    int t = threadIdx.x, tx = t & 15, ty = t >> 4, f0 = tx * 4;
    float4 acc[8];
    #pragma unroll
    for (int i = 0; i < 8; ++i) acc[i] = make_float4(0.f, 0.f, 0.f, 0.f);
    gemm_acc(xs, ws, ty, f0, acc);
    float* dst = half ? Q : P;
    float4 bias = make_float4(0.f, 0.f, 0.f, 0.f);
    if (!half) bias = *(const float4*)(mb1 + f0);
    #pragma unroll
    for (int i = 0; i < 8; ++i) {
        int m = m0 + i * 16 + ty;
        if (m < N_NODES) {
            float4 c = acc[i];
            c.x += bias.x; c.y += bias.y; c.z += bias.z; c.w += bias.w;
            *(float4*)(dst + (size_t)m * 64 + f0) = c;
        }
    }
}

// Edge aggregation: one wave per node; hmean = mean(relu(P_i + Q_j + dpos@W1p)).
__global__ void __launch_bounds__(256) k_c1(const float4* __restrict__ pos4,
                                            const float* __restrict__ mw1,
                                            const float* __restrict__ Q,
                                            const int* __restrict__ off,
                                            const int* __restrict__ sj,
                                            float* Phm) {
    int wave = threadIdx.x >> 6, lane = threadIdx.x & 63;
    int node = blockIdx.x * 4 + wave;
    if (node >= N_NODES) return;
    float Pv  = Phm[(size_t)node * 64 + lane];
    float wpx = mw1[128 * 64 + lane];
    float wpy = mw1[129 * 64 + lane];
    float wpz = mw1[130 * 64 + lane];
    float4 pi = pos4[node];
    int o0 = off[node], o1 = off[node + 1];
    float acc = 0.f;
    for (int base = o0; base < o1; base += 64) {
        int m = min(64, o1 - base);
        int jvv = (lane < m) ? sj[base + lane] : 0;
        #pragma unroll 4
        for (int c = 0; c < m; ++c) {
            int jc = __builtin_amdgcn_readlane(jvv, c);
            float4 pj = pos4[jc];
            float pre = Pv + Q[(size_t)jc * 64 + lane]
                      + (pj.x - pi.x) * wpx + (pj.y - pi.y) * wpy + (pj.z - pi.z) * wpz;
            acc += fmaxf(pre, 0.f);
        }
    }
    int dg = o1 - o0;
    Phm[(size_t)node * 64 + lane] = (dg > 0) ? acc / (float)dg : 0.f;
}

// out = relu(x@aw1_top + hm@wcomb + ab1 + [deg>0]*bcomb) @ aw2 + ab2
__global__ void __launch_bounds__(256) k_c2(const float* __restrict__ x,
                                            const float* hm_in,
                                            const float* __restrict__ aw1,
                                            const float* __restrict__ ab1,
                                            const float* __restrict__ wcomb,
                                            const float* __restrict__ bcomb,
                                            const float* __restrict__ aw2,
                                            const float* __restrict__ ab2,
                                            const int* __restrict__ deg,
                                            float* out) {
    __shared__ float xs[128 * XP];
    __shared__ float ws[64 * 64];
    int m0 = blockIdx.x * 128;
    int t = threadIdx.x, tx = t & 15, ty = t >> 4, f0 = tx * 4;
    float4 acc[8];
    #pragma unroll
    for (int i = 0; i < 8; ++i) acc[i] = make_float4(0.f, 0.f, 0.f, 0.f);

    stage_x(xs, x, m0);
    stage_w(ws, aw1);
    __syncthreads();
    gemm_acc(xs, ws, ty, f0, acc);
    __syncthreads();

    stage_x(xs, hm_in, m0);
    stage_w(ws, wcomb);
    __syncthreads();
    gemm_acc(xs, ws, ty, f0, acc);
    __syncthreads();

    float4 b1v = *(const float4*)(ab1 + f0);
    float4 bcv = *(const float4*)(bcomb + f0);
    #pragma unroll
    for (int i = 0; i < 8; ++i) {
        int m = m0 + i * 16 + ty;
        int dg = (m < N_NODES) ? deg[m] : 0;
        float4 c = acc[i];
        float bx = b1v.x, by = b1v.y, bz = b1v.z, bw = b1v.w;
        if (dg > 0) { bx += bcv.x; by += bcv.y; bz += bcv.z; bw += bcv.w; }
        c.x = fmaxf(c.x + bx, 0.f);
        c.y = fmaxf(c.y + by, 0.f);
        c.z = fmaxf(c.z + bz, 0.f);
        c.w = fmaxf(c.w + bw, 0.f);
        *(float4*)(xs + (i * 16 + ty) * XP + f0) = c;
    }
    stage_w(ws, aw2);
    __syncthreads();

    float4 a2[8];
    #pragma unroll
    for (int i = 0; i < 8; ++i) a2[i] = make_float4(0.f, 0.f, 0.f, 0.f);
    gemm_acc(xs, ws, ty, f0, a2);
    float4 b2v = *(const float4*)(ab2 + f0);
    #pragma unroll
    for (int i = 0; i < 8; ++i) {
        int m = m0 + i * 16 + ty;
        if (m < N_NODES) {
            float4 c = a2[i];
            c.x += b2v.x; c.y += b2v.y; c.z += b2v.z; c.w += b2v.w;
            *(float4*)(out + (size_t)m * 64 + f0) = c;
        }
    }
}

extern "C" void kernel_launch(void* const* d_in, const int* in_sizes, int n_in,
                              void* d_out, int out_size, void* d_ws, size_t ws_size,
                              hipStream_t stream) {
    const float* x   = (const float*)d_in[0];
    const int*   ei  = (const int*)d_in[1];
    const int*   ej  = ((const int*)d_in[1]) + N_EDGES;
    const float* pos = (const float*)d_in[2];
    const float* mw1 = (const float*)d_in[3];
    const float* mb1 = (const float*)d_in[4];
    const float* mw2 = (const float*)d_in[5];
    const float* mb2 = (const float*)d_in[6];
    const float* aw1 = (const float*)d_in[7];
    const float* ab1 = (const float*)d_in[8];
    const float* aw2 = (const float*)d_in[9];
    const float* ab2 = (const float*)d_in[10];

    char* ws = (char*)d_ws;
    int*    off   = (int*)(ws + WS_OFF);
    int*    deg   = (int*)(ws + WS_DEG);
    int*    cur   = (int*)(ws + WS_CUR);
    int*    bsum  = (int*)(ws + WS_BSUM);
    int*    sj    = (int*)(ws + WS_SJ);
    float*  wcomb = (float*)(ws + WS_WCOMB);
    float*  bcomb = (float*)(ws + WS_BCOMB);
    float*  Q     = (float*)(ws + WS_Q);
    float4* pos4  = (float4*)(ws + WS_POS4);
    float*  out   = (float*)d_out;

    const int NB1 = (N_NODES + 255) / 256;   // 391
    const int NBT = (N_NODES + 127) / 128;   // 782
    const int NBP = NCHUNK * NPART;          // 784
    hipLaunchKernelGGL(k_init,  dim3(NB1), dim3(256), 0, stream, pos, deg, pos4);
    hipLaunchKernelGGL(k_count, dim3(NBP), dim3(256), 0, stream, ei, deg);
    hipLaunchKernelGGL(k_scan1, dim3(NB1), dim3(256), 0, stream, deg, off, bsum);
    hipLaunchKernelGGL(k_scan2, dim3(1), dim3(512), 0, stream, bsum, NB1);
    hipLaunchKernelGGL(k_scan3, dim3(NB1), dim3(256), 0, stream, deg, off, bsum, cur);
    hipLaunchKernelGGL(k_fill,  dim3(NBP), dim3(256), 0, stream, ei, ej, cur, sj);
    hipLaunchKernelGGL(k_wcomb, dim3(17), dim3(256), 0, stream, mw2, mb2, aw1, wcomb, bcomb);
    hipLaunchKernelGGL(k_pre,   dim3(NBT, 2), dim3(256), 0, stream, x, mw1, mb1, out, Q);
    hipLaunchKernelGGL(k_c1,    dim3((N_NODES + 3) / 4), dim3(256), 0, stream,
                       pos4, mw1, Q, off, sj, out);
    hipLaunchKernelGGL(k_c2,    dim3(NBT), dim3(256), 0, stream,
                       x, out, aw1, ab1, wcomb, bcomb, aw2, ab2, deg, out);
}

// Round 6
// 341.912 us; speedup vs baseline: 2.3599x; 1.0415x over previous
//
#include <hip/hip_runtime.h>
#include <hip/hip_fp16.h>

#define N_NODES 100000
#define N_EDGES 1600000
#define NPART 8
#define PSZ 12500          // N_NODES / NPART
#define ECHUNK 16384       // edges per block in partitioned scan
#define NCHUNK ((N_EDGES + ECHUNK - 1) / ECHUNK)   // 98

// ---------------- workspace layout (bytes) ----------------
#define WS_OFF   0                 // int[N+1]
#define WS_DEG   400016            // int[N]
#define WS_CUR   800016            // int[N]
#define WS_BSUM  1200016           // int[512]
#define WS_SJ    1202064           // int[E]        (6.4 MB)
#define WS_WCOMB 7602064           // float[64*64]
#define WS_BCOMB 7618448           // float[64]
#define WS_Q     7618704           // __half[N*64]  (12.8 MB)  total ~20.4 MB

#define XP 68   // padded LDS row pitch (floats)

__global__ void k_zero(int* deg) {
    int t = blockIdx.x * blockDim.x + threadIdx.x;
    if (t < N_NODES) deg[t] = 0;
}

// partitioned degree count: p = blockIdx%8 -> node range [p*PSZ, (p+1)*PSZ)
__global__ void __launch_bounds__(256) k_count(const int* __restrict__ ei, int* deg) {
    int p = blockIdx.x & (NPART - 1);
    int chunk = blockIdx.x / NPART;
    int lo = p * PSZ, hi = lo + PSZ;
    #pragma unroll 2
    for (int it = 0; it < ECHUNK / 1024; ++it) {
        int e0 = chunk * ECHUNK + it * 1024 + threadIdx.x * 4;
        if (e0 >= N_EDGES) break;
        int4 iv = *(const int4*)(ei + e0);
        if (iv.x >= lo && iv.x < hi) atomicAdd(&deg[iv.x], 1);
        if (iv.y >= lo && iv.y < hi) atomicAdd(&deg[iv.y], 1);
        if (iv.z >= lo && iv.z < hi) atomicAdd(&deg[iv.z], 1);
        if (iv.w >= lo && iv.w < hi) atomicAdd(&deg[iv.w], 1);
    }
}

__global__ void k_scan1(const int* __restrict__ deg, int* off, int* bsum) {
    __shared__ int s[256];
    int t = blockIdx.x * 256 + threadIdx.x;
    int v = (t < N_NODES) ? deg[t] : 0;
    s[threadIdx.x] = v;
    __syncthreads();
    for (int o = 1; o < 256; o <<= 1) {
        int add = (threadIdx.x >= o) ? s[threadIdx.x - o] : 0;
        __syncthreads();
        s[threadIdx.x] += add;
        __syncthreads();
    }
    if (t < N_NODES) off[t] = s[threadIdx.x] - v;
    if (threadIdx.x == 255) bsum[blockIdx.x] = s[255];
}

__global__ void k_scan2(int* bsum, int nb) {
    __shared__ int s[512];
    int v = (threadIdx.x < nb) ? bsum[threadIdx.x] : 0;
    s[threadIdx.x] = v;
    __syncthreads();
    for (int o = 1; o < 512; o <<= 1) {
        int add = (threadIdx.x >= o) ? s[threadIdx.x - o] : 0;
        __syncthreads();
        s[threadIdx.x] += add;
        __syncthreads();
    }
    if (threadIdx.x < nb) bsum[threadIdx.x] = s[threadIdx.x] - v;
}

__global__ void k_scan3(const int* __restrict__ deg, int* off,
                        const int* __restrict__ bsum, int* cur) {
    int t = blockIdx.x * 256 + threadIdx.x;
    if (t < N_NODES) {
        int o = off[t] + bsum[blockIdx.x];
        off[t] = o;
        cur[t] = o;
        if (t == N_NODES - 1) off[N_NODES] = o + deg[t];
    }
}

// partitioned CSR fill: stores land in the local XCD's L2 slice of sj
__global__ void __launch_bounds__(256) k_fill(const int* __restrict__ ei,
                                              const int* __restrict__ ej,
                                              int* cur, int* sj) {
    int p = blockIdx.x & (NPART - 1);
    int chunk = blockIdx.x / NPART;
    int lo = p * PSZ, hi = lo + PSZ;
    #pragma unroll 2
    for (int it = 0; it < ECHUNK / 1024; ++it) {
        int e0 = chunk * ECHUNK + it * 1024 + threadIdx.x * 4;
        if (e0 >= N_EDGES) break;
        int4 iv = *(const int4*)(ei + e0);
        int4 jv = *(const int4*)(ej + e0);
        if (iv.x >= lo && iv.x < hi) sj[atomicAdd(&cur[iv.x], 1)] = jv.x;
        if (iv.y >= lo && iv.y < hi) sj[atomicAdd(&cur[iv.y], 1)] = jv.y;
        if (iv.z >= lo && iv.z < hi) sj[atomicAdd(&cur[iv.z], 1)] = jv.z;
        if (iv.w >= lo && iv.w < hi) sj[atomicAdd(&cur[iv.w], 1)] = jv.w;
    }
}

__global__ void k_wcomb(const float* __restrict__ mw2, const float* __restrict__ mb2,
                        const float* __restrict__ aw1, float* wcomb, float* bcomb) {
    int o = blockIdx.x * blockDim.x + threadIdx.x;
    if (o < 64 * 64) {
        int c = o >> 6, k = o & 63;
        float s = 0.f;
        #pragma unroll 8
        for (int a = 0; a < 64; ++a) s += mw2[c * 64 + a] * aw1[(64 + a) * 64 + k];
        wcomb[o] = s;
    } else if (o < 64 * 64 + 64) {
        int k = o - 64 * 64;
        float s = 0.f;
        #pragma unroll 8
        for (int a = 0; a < 64; ++a) s += mb2[a] * aw1[(64 + a) * 64 + k];
        bcomb[k] = s;
    }
}

// ---- tiled GEMM blocks: BM=128, BN=64, thread tile 8m x 4f ----
__device__ __forceinline__ void stage_x(float* xs, const float* src, int m0) {
    int t = threadIdx.x;
    #pragma unroll
    for (int it = 0; it < 8; ++it) {
        int idx = it * 256 + t;
        int m = idx >> 4;
        int q = idx & 15;
        float4 v = make_float4(0.f, 0.f, 0.f, 0.f);
        if (m0 + m < N_NODES) v = *(const float4*)(src + (size_t)(m0 + m) * 64 + q * 4);
        *(float4*)(xs + m * XP + q * 4) = v;
    }
}

__device__ __forceinline__ void stage_w(float* ws, const float* src) {
    int t = threadIdx.x;
    #pragma unroll
    for (int it = 0; it < 4; ++it) {
        int idx = it * 256 + t;
        *(float4*)(ws + idx * 4) = *(const float4*)(src + idx * 4);
    }
}

__device__ __forceinline__ void gemm_acc(const float* xs, const float* ws,
                                         int ty, int f0, float4 acc[8]) {
    #pragma unroll 4
    for (int k4 = 0; k4 < 64; k4 += 4) {
        float4 b0 = *(const float4*)(ws + (k4 + 0) * 64 + f0);
        float4 b1 = *(const float4*)(ws + (k4 + 1) * 64 + f0);
        float4 b2 = *(const float4*)(ws + (k4 + 2) * 64 + f0);
        float4 b3 = *(const float4*)(ws + (k4 + 3) * 64 + f0);
        #pragma unroll
        for (int i = 0; i < 8; ++i) {
            float4 a = *(const float4*)(xs + (i * 16 + ty) * XP + k4);
            float4 c = acc[i];
            c.x = fmaf(a.x, b0.x, c.x); c.y = fmaf(a.x, b0.y, c.y);
            c.z = fmaf(a.x, b0.z, c.z); c.w = fmaf(a.x, b0.w, c.w);
            c.x = fmaf(a.y, b1.x, c.x); c.y = fmaf(a.y, b1.y, c.y);
            c.z = fmaf(a.y, b1.z, c.z); c.w = fmaf(a.y, b1.w, c.w);
            c.x = fmaf(a.z, b2.x, c.x); c.y = fmaf(a.z, b2.y, c.y);
            c.z = fmaf(a.z, b2.z, c.z); c.w = fmaf(a.z, b2.w, c.w);
            c.x = fmaf(a.w, b3.x, c.x); c.y = fmaf(a.w, b3.y, c.y);
            c.z = fmaf(a.w, b3.z, c.z); c.w = fmaf(a.w, b3.w, c.w);
            acc[i] = c;
        }
    }
}

// y=0: P' = x@mw1[0:64]  + mb1 - pos@W1p  -> d_out temp (fp32)
// y=1: Q' = x@mw1[64:128]      + pos@W1p  -> ws Q (fp16)
__global__ void __launch_bounds__(256) k_pre(const float* __restrict__ x,
                                             const float* __restrict__ pos,
                                             const float* __restrict__ mw1,
                                             const float* __restrict__ mb1,
                                             float* __restrict__ P,
                                             __half* __restrict__ Q16) {
    __shared__ float xs[128 * XP];
    __shared__ float ws[64 * 64];
    int half = blockIdx.y;
    int m0 = blockIdx.x * 128;
    stage_x(xs, x, m0);
    stage_w(ws, mw1 + half * 4096);
    __syncthreads();
    int t = threadIdx.x, tx = t & 15, ty = t >> 4, f0 = tx * 4;
    float4 acc[8];
    #pragma unroll
    for (int i = 0; i < 8; ++i) acc[i] = make_float4(0.f, 0.f, 0.f, 0.f);
    gemm_acc(xs, ws, ty, f0, acc);

    // pos-projection fold: wp rows 128..130 of mw1
    float4 wpx = *(const float4*)(mw1 + 128 * 64 + f0);
    float4 wpy = *(const float4*)(mw1 + 129 * 64 + f0);
    float4 wpz = *(const float4*)(mw1 + 130 * 64 + f0);
    float sg = half ? 1.f : -1.f;
    float4 bias = make_float4(0.f, 0.f, 0.f, 0.f);
    if (!half) bias = *(const float4*)(mb1 + f0);

    #pragma unroll
    for (int i = 0; i < 8; ++i) {
        int m = m0 + i * 16 + ty;
        if (m >= N_NODES) continue;
        float px = pos[3 * m], py = pos[3 * m + 1], pz = pos[3 * m + 2];
        float4 c = acc[i];
        c.x += bias.x + sg * (px * wpx.x + py * wpy.x + pz * wpz.x);
        c.y += bias.y + sg * (px * wpx.y + py * wpy.y + pz * wpz.y);
        c.z += bias.z + sg * (px * wpx.z + py * wpy.z + pz * wpz.z);
        c.w += bias.w + sg * (px * wpx.w + py * wpy.w + pz * wpz.w);
        if (half) {
            uint lo = ((uint)__half_as_ushort(__float2half_rn(c.y)) << 16)
                    | (uint)__half_as_ushort(__float2half_rn(c.x));
            uint hi = ((uint)__half_as_ushort(__float2half_rn(c.w)) << 16)
                    | (uint)__half_as_ushort(__float2half_rn(c.z));
            *(uint2*)((unsigned short*)Q16 + (size_t)m * 64 + f0) = make_uint2(lo, hi);
        } else {
            *(float4*)(P + (size_t)m * 64 + f0) = c;
        }
    }
}

// Edge aggregation: one wave per node; hmean = mean(relu(P'_i + Q'_j)).
__global__ void __launch_bounds__(256) k_c1(const __half* __restrict__ Q16,
                                            const int* __restrict__ off,
                                            const int* __restrict__ sj,
                                            float* Phm) {
    int wave = threadIdx.x >> 6, lane = threadIdx.x & 63;
    int node = blockIdx.x * 4 + wave;
    if (node >= N_NODES) return;
    float Pv = Phm[(size_t)node * 64 + lane];
    int o0 = off[node], o1 = off[node + 1];
    float acc = 0.f;
    for (int base = o0; base < o1; base += 64) {
        int m = min(64, o1 - base);
        int jvv = (lane < m) ? sj[base + lane] : 0;
        #pragma unroll 8
        for (int c = 0; c < m; ++c) {
            int jc = __builtin_amdgcn_readlane(jvv, c);
            float qv = __half2float(Q16[(size_t)jc * 64 + lane]);
            acc += fmaxf(Pv + qv, 0.f);
        }
    }
    int dg = o1 - o0;
    Phm[(size_t)node * 64 + lane] = (dg > 0) ? acc / (float)dg : 0.f;
}

// out = relu(x@aw1_top + hm@wcomb + ab1 + [deg>0]*bcomb) @ aw2 + ab2
__global__ void __launch_bounds__(256) k_c2(const float* __restrict__ x,
                                            const float* hm_in,
                                            const float* __restrict__ aw1,
                                            const float* __restrict__ ab1,
                                            const float* __restrict__ wcomb,
                                            const float* __restrict__ bcomb,
                                            const float* __restrict__ aw2,
                                            const float* __restrict__ ab2,
                                            const int* __restrict__ deg,
                                            float* out) {
    __shared__ float xs[128 * XP];
    __shared__ float ws[64 * 64];
    int m0 = blockIdx.x * 128;
    int t = threadIdx.x, tx = t & 15, ty = t >> 4, f0 = tx * 4;
    float4 acc[8];
    #pragma unroll
    for (int i = 0; i < 8; ++i) acc[i] = make_float4(0.f, 0.f, 0.f, 0.f);

    stage_x(xs, x, m0);
    stage_w(ws, aw1);
    __syncthreads();
    gemm_acc(xs, ws, ty, f0, acc);
    __syncthreads();

    stage_x(xs, hm_in, m0);
    stage_w(ws, wcomb);
    __syncthreads();
    gemm_acc(xs, ws, ty, f0, acc);
    __syncthreads();

    float4 b1v = *(const float4*)(ab1 + f0);
    float4 bcv = *(const float4*)(bcomb + f0);
    #pragma unroll
    for (int i = 0; i < 8; ++i) {
        int m = m0 + i * 16 + ty;
        int dg = (m < N_NODES) ? deg[m] : 0;
        float4 c = acc[i];
        float bx = b1v.x, by = b1v.y, bz = b1v.z, bw = b1v.w;
        if (dg > 0) { bx += bcv.x; by += bcv.y; bz += bcv.z; bw += bcv.w; }
        c.x = fmaxf(c.x + bx, 0.f);
        c.y = fmaxf(c.y + by, 0.f);
        c.z = fmaxf(c.z + bz, 0.f);
        c.w = fmaxf(c.w + bw, 0.f);
        *(float4*)(xs + (i * 16 + ty) * XP + f0) = c;
    }
    stage_w(ws, aw2);
    __syncthreads();

    float4 a2[8];
    #pragma unroll
    for (int i = 0; i < 8; ++i) a2[i] = make_float4(0.f, 0.f, 0.f, 0.f);
    gemm_acc(xs, ws, ty, f0, a2);
    float4 b2v = *(const float4*)(ab2 + f0);
    #pragma unroll
    for (int i = 0; i < 8; ++i) {
        int m = m0 + i * 16 + ty;
        if (m < N_NODES) {
            float4 c = a2[i];
            c.x += b2v.x; c.y += b2v.y; c.z += b2v.z; c.w += b2v.w;
            *(float4*)(out + (size_t)m * 64 + f0) = c;
        }
    }
}

extern "C" void kernel_launch(void* const* d_in, const int* in_sizes, int n_in,
                              void* d_out, int out_size, void* d_ws, size_t ws_size,
                              hipStream_t stream) {
    const float* x   = (const float*)d_in[0];
    const int*   ei  = (const int*)d_in[1];
    const int*   ej  = ((const int*)d_in[1]) + N_EDGES;
    const float* pos = (const float*)d_in[2];
    const float* mw1 = (const float*)d_in[3];
    const float* mb1 = (const float*)d_in[4];
    const float* mw2 = (const float*)d_in[5];
    const float* mb2 = (const float*)d_in[6];
    const float* aw1 = (const float*)d_in[7];
    const float* ab1 = (const float*)d_in[8];
    const float* aw2 = (const float*)d_in[9];
    const float* ab2 = (const float*)d_in[10];

    char* ws = (char*)d_ws;
    int*    off   = (int*)(ws + WS_OFF);
    int*    deg   = (int*)(ws + WS_DEG);
    int*    cur   = (int*)(ws + WS_CUR);
    int*    bsum  = (int*)(ws + WS_BSUM);
    int*    sj    = (int*)(ws + WS_SJ);
    float*  wcomb = (float*)(ws + WS_WCOMB);
    float*  bcomb = (float*)(ws + WS_BCOMB);
    __half* Q16   = (__half*)(ws + WS_Q);
    float*  out   = (float*)d_out;

    const int NB1 = (N_NODES + 255) / 256;   // 391
    const int NBT = (N_NODES + 127) / 128;   // 782
    const int NBP = NCHUNK * NPART;          // 784
    hipLaunchKernelGGL(k_zero,  dim3(NB1), dim3(256), 0, stream, deg);
    hipLaunchKernelGGL(k_count, dim3(NBP), dim3(256), 0, stream, ei, deg);
    hipLaunchKernelGGL(k_scan1, dim3(NB1), dim3(256), 0, stream, deg, off, bsum);
    hipLaunchKernelGGL(k_scan2, dim3(1), dim3(512), 0, stream, bsum, NB1);
    hipLaunchKernelGGL(k_scan3, dim3(NB1), dim3(256), 0, stream, deg, off, bsum, cur);
    hipLaunchKernelGGL(k_fill,  dim3(NBP), dim3(256), 0, stream, ei, ej, cur, sj);
    hipLaunchKernelGGL(k_wcomb, dim3(17), dim3(256), 0, stream, mw2, mb2, aw1, wcomb, bcomb);
    hipLaunchKernelGGL(k_pre,   dim3(NBT, 2), dim3(256), 0, stream, x, pos, mw1, mb1, out, Q16);
    hipLaunchKernelGGL(k_c1,    dim3((N_NODES + 3) / 4), dim3(256), 0, stream,
                       Q16, off, sj, out);
    hipLaunchKernelGGL(k_c2,    dim3(NBT), dim3(256), 0, stream,
                       x, out, aw1, ab1, wcomb, bcomb, aw2, ab2, deg, out);
}

// Round 7
// 298.809 us; speedup vs baseline: 2.7003x; 1.1442x over previous
//
#include <hip/hip_runtime.h>
#include <hip/hip_fp16.h>

#define N_NODES 100000
#define N_EDGES 1600000
#define NPART 8
#define PSZ 12500
#define ECHUNK 16384
#define NCHUNK ((N_EDGES + ECHUNK - 1) / ECHUNK)   // 98

// ---------------- workspace layout (bytes) ----------------
#define WS_OFF   0                 // int[N+1]
#define WS_DEG   400016            // int[N]
#define WS_CUR   800016            // int[N]
#define WS_BSUM  1200016           // int[512]
#define WS_SJ    1202064           // int[E]        (6.4 MB)
#define WS_WCOMB 7602064           // float[64*64]
#define WS_BCOMB 7618448           // float[64]
#define WS_Q     7618704           // __half[N*64]  (12.8 MB)

#define XP 68   // padded LDS row pitch (floats)

__global__ void k_zero(int* deg) {
    int t = blockIdx.x * blockDim.x + threadIdx.x;
    if (t < N_NODES) deg[t] = 0;
}

__global__ void __launch_bounds__(256) k_count(const int* __restrict__ ei, int* deg) {
    int p = blockIdx.x & (NPART - 1);
    int chunk = blockIdx.x / NPART;
    int lo = p * PSZ, hi = lo + PSZ;
    #pragma unroll 2
    for (int it = 0; it < ECHUNK / 1024; ++it) {
        int e0 = chunk * ECHUNK + it * 1024 + threadIdx.x * 4;
        if (e0 >= N_EDGES) break;
        int4 iv = *(const int4*)(ei + e0);
        if (iv.x >= lo && iv.x < hi) atomicAdd(&deg[iv.x], 1);
        if (iv.y >= lo && iv.y < hi) atomicAdd(&deg[iv.y], 1);
        if (iv.z >= lo && iv.z < hi) atomicAdd(&deg[iv.z], 1);
        if (iv.w >= lo && iv.w < hi) atomicAdd(&deg[iv.w], 1);
    }
}

__global__ void k_scan1(const int* __restrict__ deg, int* off, int* bsum) {
    __shared__ int s[256];
    int t = blockIdx.x * 256 + threadIdx.x;
    int v = (t < N_NODES) ? deg[t] : 0;
    s[threadIdx.x] = v;
    __syncthreads();
    for (int o = 1; o < 256; o <<= 1) {
        int add = (threadIdx.x >= o) ? s[threadIdx.x - o] : 0;
        __syncthreads();
        s[threadIdx.x] += add;
        __syncthreads();
    }
    if (t < N_NODES) off[t] = s[threadIdx.x] - v;
    if (threadIdx.x == 255) bsum[blockIdx.x] = s[255];
}

__global__ void k_scan2(int* bsum, int nb) {
    __shared__ int s[512];
    int v = (threadIdx.x < nb) ? bsum[threadIdx.x] : 0;
    s[threadIdx.x] = v;
    __syncthreads();
    for (int o = 1; o < 512; o <<= 1) {
        int add = (threadIdx.x >= o) ? s[threadIdx.x - o] : 0;
        __syncthreads();
        s[threadIdx.x] += add;
        __syncthreads();
    }
    if (threadIdx.x < nb) bsum[threadIdx.x] = s[threadIdx.x] - v;
}

__global__ void k_scan3(const int* __restrict__ deg, int* off,
                        const int* __restrict__ bsum, int* cur) {
    int t = blockIdx.x * 256 + threadIdx.x;
    if (t < N_NODES) {
        int o = off[t] + bsum[blockIdx.x];
        off[t] = o;
        cur[t] = o;
        if (t == N_NODES - 1) off[N_NODES] = o + deg[t];
    }
}

__global__ void __launch_bounds__(256) k_fill(const int* __restrict__ ei,
                                              const int* __restrict__ ej,
                                              int* cur, int* sj) {
    int p = blockIdx.x & (NPART - 1);
    int chunk = blockIdx.x / NPART;
    int lo = p * PSZ, hi = lo + PSZ;
    #pragma unroll 2
    for (int it = 0; it < ECHUNK / 1024; ++it) {
        int e0 = chunk * ECHUNK + it * 1024 + threadIdx.x * 4;
        if (e0 >= N_EDGES) break;
        int4 iv = *(const int4*)(ei + e0);
        int4 jv = *(const int4*)(ej + e0);
        if (iv.x >= lo && iv.x < hi) sj[atomicAdd(&cur[iv.x], 1)] = jv.x;
        if (iv.y >= lo && iv.y < hi) sj[atomicAdd(&cur[iv.y], 1)] = jv.y;
        if (iv.z >= lo && iv.z < hi) sj[atomicAdd(&cur[iv.z], 1)] = jv.z;
        if (iv.w >= lo && iv.w < hi) sj[atomicAdd(&cur[iv.w], 1)] = jv.w;
    }
}

__global__ void k_wcomb(const float* __restrict__ mw2, const float* __restrict__ mb2,
                        const float* __restrict__ aw1, float* wcomb, float* bcomb) {
    int o = blockIdx.x * blockDim.x + threadIdx.x;
    if (o < 64 * 64) {
        int c = o >> 6, k = o & 63;
        float s = 0.f;
        #pragma unroll 8
        for (int a = 0; a < 64; ++a) s += mw2[c * 64 + a] * aw1[(64 + a) * 64 + k];
        wcomb[o] = s;
    } else if (o < 64 * 64 + 64) {
        int k = o - 64 * 64;
        float s = 0.f;
        #pragma unroll 8
        for (int a = 0; a < 64; ++a) s += mb2[a] * aw1[(64 + a) * 64 + k];
        bcomb[k] = s;
    }
}

// ---- tiled GEMM blocks: BM=128, BN=64, thread tile 8m x 4f ----
__device__ __forceinline__ void stage_x(float* xs, const float* src, int m0) {
    int t = threadIdx.x;
    #pragma unroll
    for (int it = 0; it < 8; ++it) {
        int idx = it * 256 + t;
        int m = idx >> 4;
        int q = idx & 15;
        float4 v = make_float4(0.f, 0.f, 0.f, 0.f);
        if (m0 + m < N_NODES) v = *(const float4*)(src + (size_t)(m0 + m) * 64 + q * 4);
        *(float4*)(xs + m * XP + q * 4) = v;
    }
}

__device__ __forceinline__ void stage_w(float* ws, const float* src) {
    int t = threadIdx.x;
    #pragma unroll
    for (int it = 0; it < 4; ++it) {
        int idx = it * 256 + t;
        *(float4*)(ws + idx * 4) = *(const float4*)(src + idx * 4);
    }
}

__device__ __forceinline__ void gemm_acc(const float* xs, const float* ws,
                                         int ty, int f0, float4 acc[8]) {
    #pragma unroll 4
    for (int k4 = 0; k4 < 64; k4 += 4) {
        float4 b0 = *(const float4*)(ws + (k4 + 0) * 64 + f0);
        float4 b1 = *(const float4*)(ws + (k4 + 1) * 64 + f0);
        float4 b2 = *(const float4*)(ws + (k4 + 2) * 64 + f0);
        float4 b3 = *(const float4*)(ws + (k4 + 3) * 64 + f0);
        #pragma unroll
        for (int i = 0; i < 8; ++i) {
            float4 a = *(const float4*)(xs + (i * 16 + ty) * XP + k4);
            float4 c = acc[i];
            c.x = fmaf(a.x, b0.x, c.x); c.y = fmaf(a.x, b0.y, c.y);
            c.z = fmaf(a.x, b0.z, c.z); c.w = fmaf(a.x, b0.w, c.w);
            c.x = fmaf(a.y, b1.x, c.x); c.y = fmaf(a.y, b1.y, c.y);
            c.z = fmaf(a.y, b1.z, c.z); c.w = fmaf(a.y, b1.w, c.w);
            c.x = fmaf(a.z, b2.x, c.x); c.y = fmaf(a.z, b2.y, c.y);
            c.z = fmaf(a.z, b2.z, c.z); c.w = fmaf(a.z, b2.w, c.w);
            c.x = fmaf(a.w, b3.x, c.x); c.y = fmaf(a.w, b3.y, c.y);
            c.z = fmaf(a.w, b3.z, c.z); c.w = fmaf(a.w, b3.w, c.w);
            acc[i] = c;
        }
    }
}

// Fused: P' = x@W1a + mb1 - pos@W1p (fp32 -> d_out temp)
//        Q' = x@W1b       + pos@W1p (fp16 -> ws Q)
// One x staging for both halves.
__global__ void __launch_bounds__(256) k_pre(const float* __restrict__ x,
                                             const float* __restrict__ pos,
                                             const float* __restrict__ mw1,
                                             const float* __restrict__ mb1,
                                             float* __restrict__ P,
                                             __half* __restrict__ Q16) {
    __shared__ float xs[128 * XP];
    __shared__ float ws[64 * 64];
    int m0 = blockIdx.x * 128;
    int t = threadIdx.x, tx = t & 15, ty = t >> 4, f0 = tx * 4;

    stage_x(xs, x, m0);
    stage_w(ws, mw1);                 // W1a
    __syncthreads();
    float4 accP[8];
    #pragma unroll
    for (int i = 0; i < 8; ++i) accP[i] = make_float4(0.f, 0.f, 0.f, 0.f);
    gemm_acc(xs, ws, ty, f0, accP);
    __syncthreads();
    stage_w(ws, mw1 + 4096);          // W1b
    __syncthreads();
    float4 accQ[8];
    #pragma unroll
    for (int i = 0; i < 8; ++i) accQ[i] = make_float4(0.f, 0.f, 0.f, 0.f);
    gemm_acc(xs, ws, ty, f0, accQ);

    float4 wpx = *(const float4*)(mw1 + 128 * 64 + f0);
    float4 wpy = *(const float4*)(mw1 + 129 * 64 + f0);
    float4 wpz = *(const float4*)(mw1 + 130 * 64 + f0);
    float4 bias = *(const float4*)(mb1 + f0);

    #pragma unroll
    for (int i = 0; i < 8; ++i) {
        int m = m0 + i * 16 + ty;
        if (m >= N_NODES) continue;
        float px = pos[3 * m], py = pos[3 * m + 1], pz = pos[3 * m + 2];
        float dx = px * wpx.x + py * wpy.x + pz * wpz.x;
        float dy = px * wpx.y + py * wpy.y + pz * wpz.y;
        float dz = px * wpx.z + py * wpy.z + pz * wpz.z;
        float dw = px * wpx.w + py * wpy.w + pz * wpz.w;
        float4 cp = accP[i];
        cp.x += bias.x - dx; cp.y += bias.y - dy;
        cp.z += bias.z - dz; cp.w += bias.w - dw;
        *(float4*)(P + (size_t)m * 64 + f0) = cp;
        float4 cq = accQ[i];
        cq.x += dx; cq.y += dy; cq.z += dz; cq.w += dw;
        uint lo = ((uint)__half_as_ushort(__float2half_rn(cq.y)) << 16)
                | (uint)__half_as_ushort(__float2half_rn(cq.x));
        uint hi = ((uint)__half_as_ushort(__float2half_rn(cq.w)) << 16)
                | (uint)__half_as_ushort(__float2half_rn(cq.z));
        *(uint2*)((unsigned short*)Q16 + (size_t)m * 64 + f0) = make_uint2(lo, hi);
    }
}

// Edge aggregation: one wave per node; hmean = mean(relu(P'_i + Q'_j)).
// Inner loop has STATIC trip count (16) so the compiler fully unrolls and
// issues 16 independent gathers per group (MLP), instead of one latency
// chain per edge.
__global__ void __launch_bounds__(256) k_c1(const __half* __restrict__ Q16,
                                            const int* __restrict__ off,
                                            const int* __restrict__ sj,
                                            float* Phm) {
    int wave = threadIdx.x >> 6, lane = threadIdx.x & 63;
    int node = blockIdx.x * 4 + wave;
    if (node >= N_NODES) return;
    float Pv = Phm[(size_t)node * 64 + lane];
    int o0 = off[node], o1 = off[node + 1];
    int dg = o1 - o0;
    float acc = 0.f;
    for (int base = o0; base < o1; base += 64) {
        int m = min(64, o1 - base);
        int jvv = (lane < m) ? sj[base + lane] : 0;
        for (int g = 0; g < 64; g += 16) {
            if (g >= m) break;
            float v[16];
            #pragma unroll
            for (int cc = 0; cc < 16; ++cc) {
                int jc = __builtin_amdgcn_readlane(jvv, g + cc);  // const lane idx
                v[cc] = __half2float(Q16[(size_t)jc * 64 + lane]);
            }
            #pragma unroll
            for (int cc = 0; cc < 16; ++cc) {
                float r = fmaxf(Pv + v[cc], 0.f);
                acc += (g + cc < m) ? r : 0.f;
            }
        }
    }
    Phm[(size_t)node * 64 + lane] = (dg > 0) ? acc / (float)dg : 0.f;
}

// out = relu(x@aw1_top + hm@wcomb + ab1 + [deg>0]*bcomb) @ aw2 + ab2
__global__ void __launch_bounds__(256) k_c2(const float* __restrict__ x,
                                            const float* hm_in,
                                            const float* __restrict__ aw1,
                                            const float* __restrict__ ab1,
                                            const float* __restrict__ wcomb,
                                            const float* __restrict__ bcomb,
                                            const float* __restrict__ aw2,
                                            const float* __restrict__ ab2,
                                            const int* __restrict__ deg,
                                            float* out) {
    __shared__ float xs[128 * XP];
    __shared__ float ws[64 * 64];
    int m0 = blockIdx.x * 128;
    int t = threadIdx.x, tx = t & 15, ty = t >> 4, f0 = tx * 4;
    float4 acc[8];
    #pragma unroll
    for (int i = 0; i < 8; ++i) acc[i] = make_float4(0.f, 0.f, 0.f, 0.f);

    stage_x(xs, x, m0);
    stage_w(ws, aw1);
    __syncthreads();
    gemm_acc(xs, ws, ty, f0, acc);
    __syncthreads();

    stage_x(xs, hm_in, m0);
    stage_w(ws, wcomb);
    __syncthreads();
    gemm_acc(xs, ws, ty, f0, acc);
    __syncthreads();

    float4 b1v = *(const float4*)(ab1 + f0);
    float4 bcv = *(const float4*)(bcomb + f0);
    #pragma unroll
    for (int i = 0; i < 8; ++i) {
        int m = m0 + i * 16 + ty;
        int dg = (m < N_NODES) ? deg[m] : 0;
        float4 c = acc[i];
        float bx = b1v.x, by = b1v.y, bz = b1v.z, bw = b1v.w;
        if (dg > 0) { bx += bcv.x; by += bcv.y; bz += bcv.z; bw += bcv.w; }
        c.x = fmaxf(c.x + bx, 0.f);
        c.y = fmaxf(c.y + by, 0.f);
        c.z = fmaxf(c.z + bz, 0.f);
        c.w = fmaxf(c.w + bw, 0.f);
        *(float4*)(xs + (i * 16 + ty) * XP + f0) = c;
    }
    stage_w(ws, aw2);
    __syncthreads();

    float4 a2[8];
    #pragma unroll
    for (int i = 0; i < 8; ++i) a2[i] = make_float4(0.f, 0.f, 0.f, 0.f);
    gemm_acc(xs, ws, ty, f0, a2);
    float4 b2v = *(const float4*)(ab2 + f0);
    #pragma unroll
    for (int i = 0; i < 8; ++i) {
        int m = m0 + i * 16 + ty;
        if (m < N_NODES) {
            float4 c = a2[i];
            c.x += b2v.x; c.y += b2v.y; c.z += b2v.z; c.w += b2v.w;
            *(float4*)(out + (size_t)m * 64 + f0) = c;
        }
    }
}

extern "C" void kernel_launch(void* const* d_in, const int* in_sizes, int n_in,
                              void* d_out, int out_size, void* d_ws, size_t ws_size,
                              hipStream_t stream) {
    const float* x   = (const float*)d_in[0];
    const int*   ei  = (const int*)d_in[1];
    const int*   ej  = ((const int*)d_in[1]) + N_EDGES;
    const float* pos = (const float*)d_in[2];
    const float* mw1 = (const float*)d_in[3];
    const float* mb1 = (const float*)d_in[4];
    const float* mw2 = (const float*)d_in[5];
    const float* mb2 = (const float*)d_in[6];
    const float* aw1 = (const float*)d_in[7];
    const float* ab1 = (const float*)d_in[8];
    const float* aw2 = (const float*)d_in[9];
    const float* ab2 = (const float*)d_in[10];

    char* ws = (char*)d_ws;
    int*    off   = (int*)(ws + WS_OFF);
    int*    deg   = (int*)(ws + WS_DEG);
    int*    cur   = (int*)(ws + WS_CUR);
    int*    bsum  = (int*)(ws + WS_BSUM);
    int*    sj    = (int*)(ws + WS_SJ);
    float*  wcomb = (float*)(ws + WS_WCOMB);
    float*  bcomb = (float*)(ws + WS_BCOMB);
    __half* Q16   = (__half*)(ws + WS_Q);
    float*  out   = (float*)d_out;

    const int NB1 = (N_NODES + 255) / 256;   // 391
    const int NBT = (N_NODES + 127) / 128;   // 782
    const int NBP = NCHUNK * NPART;          // 784
    hipLaunchKernelGGL(k_zero,  dim3(NB1), dim3(256), 0, stream, deg);
    hipLaunchKernelGGL(k_count, dim3(NBP), dim3(256), 0, stream, ei, deg);
    hipLaunchKernelGGL(k_scan1, dim3(NB1), dim3(256), 0, stream, deg, off, bsum);
    hipLaunchKernelGGL(k_scan2, dim3(1), dim3(512), 0, stream, bsum, NB1);
    hipLaunchKernelGGL(k_scan3, dim3(NB1), dim3(256), 0, stream, deg, off, bsum, cur);
    hipLaunchKernelGGL(k_fill,  dim3(NBP), dim3(256), 0, stream, ei, ej, cur, sj);
    hipLaunchKernelGGL(k_wcomb, dim3(17), dim3(256), 0, stream, mw2, mb2, aw1, wcomb, bcomb);
    hipLaunchKernelGGL(k_pre,   dim3(NBT), dim3(256), 0, stream, x, pos, mw1, mb1, out, Q16);
    hipLaunchKernelGGL(k_c1,    dim3((N_NODES + 3) / 4), dim3(256), 0, stream,
                       Q16, off, sj, out);
    hipLaunchKernelGGL(k_c2,    dim3(NBT), dim3(256), 0, stream,
                       x, out, aw1, ab1, wcomb, bcomb, aw2, ab2, deg, out);
}